// Round 7
// baseline (173.932 us; speedup 1.0000x reference)
//
#include <hip/hip_runtime.h>
#include <hip/hip_bf16.h>
#include <math.h>
#include <stdint.h>

// Shapes: B=64, T=256, R=49, H=1024
// out = [c_t (B*T*H fp32)] ++ [alpha (B*T*R fp32)]
// ws  = [cv fp32 3136x49][cg fp32 16384x49][vT bf16 64x1024x64 swizzled] (~12.2 MB)
//
// Round 7: revert cg GEMM to round-5 M64 (M128 regressed: LDS/VGPR occupancy).
// zsoftmax_ct: t-tile 8, grid 2048, 1 t-row/wave in phase 1 (halves the serial
// tanh+reduce chain per block; occupancy unchanged at 4 blk/CU). Al rows 8..15
// zero-filled so phase-2 fragment math is byte-identical; stores guarded quad<2.

typedef __attribute__((ext_vector_type(8))) short bf16x8;
typedef __attribute__((ext_vector_type(4))) float floatx4;

static __device__ __forceinline__ bf16x8 pack8(float4 a, float4 b) {
    union { __hip_bfloat162 h[4]; bf16x8 v; } u;
    u.h[0] = __float22bfloat162_rn(make_float2(a.x, a.y));
    u.h[1] = __float22bfloat162_rn(make_float2(a.z, a.w));
    u.h[2] = __float22bfloat162_rn(make_float2(b.x, b.y));
    u.h[3] = __float22bfloat162_rn(make_float2(b.z, b.w));
    return u.v;
}

static __device__ __forceinline__ unsigned short f2bf_bits(float f) {
    union { __hip_bfloat16 h; unsigned short u; } c;
    c.h = __float2bfloat16(f);
    return c.u;
}

// Blocks 0..48: cv = V.Wv^T (M-tile 64); 49..304: cg = h_t.Wg^T (M-tile 64);
// 305..816: transpose V -> vT[b][h][r(pad 64)] bf16, octet-swizzled rows.
// (byte-exact round-5 version)
__global__ __launch_bounds__(256) void gemm_mfma_tr(const float* __restrict__ Av,
                                                    const float* __restrict__ Ag,
                                                    const float* __restrict__ Wv,
                                                    const float* __restrict__ Wg,
                                                    float* __restrict__ Cv,
                                                    float* __restrict__ Cg,
                                                    unsigned short* __restrict__ vT) {
    __shared__ __align__(16) char smem[49 * 132 * 4];  // 25872 B, union
    const int bid = blockIdx.x;
    const int tid = threadIdx.x;

    if (bid >= 305) {
        // ---- V transpose: one (b, 128-h slice) per block ----
        float* Ts = (float*)smem;  // [49][132]
        const int tb = bid - 305;
        const int b = tb >> 3;
        const int h0 = (tb & 7) * 128;
        for (int i = tid; i < 49 * 32; i += 256) {
            const int r = i >> 5, hq = i & 31;
            *(float4*)(Ts + r * 132 + hq * 4) =
                *(const float4*)(Av + ((size_t)b * 49 + r) * 1024 + h0 + hq * 4);
        }
        __syncthreads();
        const int h = tid & 127;
        const int half = tid >> 7;  // 0: r 0..31 (octets 0..3), 1: r 32..63 (4..7)
        float f[32];
#pragma unroll
        for (int j = 0; j < 32; ++j) {
            const int r = half * 32 + j;
            f[j] = (r < 49) ? Ts[r * 132 + h] : 0.f;
        }
        const size_t rowbase = ((size_t)b * 1024 + h0 + h) * 64;
#pragma unroll
        for (int o2 = 0; o2 < 4; ++o2) {
            const int o = half * 4 + o2;
            bf16x8 v = pack8(make_float4(f[o2*8+0], f[o2*8+1], f[o2*8+2], f[o2*8+3]),
                             make_float4(f[o2*8+4], f[o2*8+5], f[o2*8+6], f[o2*8+7]));
            *(bf16x8*)(vT + rowbase + (size_t)((o ^ (h & 7)) * 8)) = v;
        }
        return;
    }

    // ---- GEMM C[m][n] = sum_k A[m][k]*W[n][k], M-tile 64, K=1024, N=49->64 ----
    short* As = (short*)smem;           // [64][64] bf16, octet-swizzled
    short* Ws = (short*)(smem + 8192);  // [64][64]
    const float* A; const float* W; float* C; int m0;
    if (bid < 49) { A = Av; W = Wv; C = Cv; m0 = bid * 64; }
    else          { A = Ag; W = Wg; C = Cg; m0 = (bid - 49) * 64; }

    const int wave = tid >> 6, lane = tid & 63;
    const int quad = lane >> 4, l16 = lane & 15;

    floatx4 acc[4] = {};  // wave owns m [wave*16,+16) x n [0,64)

    // A staging: round-2 pattern, applied to rows arow and arow+32.
    const int arow = tid >> 3, ag = tid & 7;
    const float* aptr = A + (size_t)(m0 + arow) * 1024 + ag * 8;
    const float* bptr = aptr + 32 * 1024;  // row arow+32, same octet
    // W staging: byte-identical round-2 code.
    const int wrow = tid >> 2, wq = tid & 3;
    const bool wvalid = wrow < 49;
    const float* wptr = W + (size_t)wrow * 1024 + wq * 16;

    float4 a0 = *(const float4*)(aptr);
    float4 a1 = *(const float4*)(aptr + 4);
    float4 b0 = *(const float4*)(bptr);
    float4 b1 = *(const float4*)(bptr + 4);
    float4 w0 = make_float4(0.f,0.f,0.f,0.f), w1 = w0, w2 = w0, w3 = w0;
    if (wvalid) {
        w0 = *(const float4*)(wptr);
        w1 = *(const float4*)(wptr + 4);
        w2 = *(const float4*)(wptr + 8);
        w3 = *(const float4*)(wptr + 12);
    }

    for (int kc = 0; kc < 1024; kc += 64) {
        __syncthreads();
        *(bf16x8*)(As + arow * 64 + (ag ^ (arow & 7)) * 8)        = pack8(a0, a1);
        *(bf16x8*)(As + (arow + 32) * 64 + (ag ^ (arow & 7)) * 8) = pack8(b0, b1);
        *(bf16x8*)(Ws + wrow * 64 + ((wq * 2) ^ (wrow & 7)) * 8)     = pack8(w0, w1);
        *(bf16x8*)(Ws + wrow * 64 + ((wq * 2 + 1) ^ (wrow & 7)) * 8) = pack8(w2, w3);
        __syncthreads();
        if (kc < 960) {  // prefetch next tile; latency hides under MFMA below
            a0 = *(const float4*)(aptr + kc + 64);
            a1 = *(const float4*)(aptr + kc + 68);
            b0 = *(const float4*)(bptr + kc + 64);
            b1 = *(const float4*)(bptr + kc + 68);
            if (wvalid) {
                w0 = *(const float4*)(wptr + kc + 64);
                w1 = *(const float4*)(wptr + kc + 68);
                w2 = *(const float4*)(wptr + kc + 72);
                w3 = *(const float4*)(wptr + kc + 76);
            }
        }
#pragma unroll
        for (int s = 0; s < 2; ++s) {
            const int am = wave * 16 + l16;
            bf16x8 af = *(const bf16x8*)(As + am * 64 + (((s << 2) + quad) ^ (am & 7)) * 8);
#pragma unroll
            for (int nt = 0; nt < 4; ++nt) {
                const int wn = nt * 16 + l16;
                bf16x8 bf = *(const bf16x8*)(Ws + wn * 64 + (((s << 2) + quad) ^ (wn & 7)) * 8);
                acc[nt] = __builtin_amdgcn_mfma_f32_16x16x32_bf16(af, bf, acc[nt], 0, 0, 0);
            }
        }
    }

#pragma unroll
    for (int nt = 0; nt < 4; ++nt) {
        const int n = nt * 16 + l16;
        if (n < 49) {
#pragma unroll
            for (int r = 0; r < 4; ++r) {
                const int m = m0 + wave * 16 + quad * 4 + r;
                C[(size_t)m * 49 + n] = acc[nt][r];
            }
        }
    }
}

// Fused: z[b,t,r] = sum_k tanh(cv[b,r,k]+cg[b,t,k])*Wh[k]; alpha=softmax_r(z);
// c_t[b,t,h] = sum_r alpha*V via bf16 MFMA with B-fragments read straight
// from global vT (L2-resident). Block = (b, 8-row t-tile), 512 threads/8 waves,
// ONE t-row per wave in phase 1. grid = 64*32 = 2048. XCD-chunked bid swizzle
// (256-block chunks). Al rows 8..15 zero so phase-2 fragment math is unchanged;
// phase-2 stores guarded to quad<2 (the 8 valid t-rows).
__global__ __launch_bounds__(512, 8) void zsoftmax_ct(const float* __restrict__ cv,
                                                      const float* __restrict__ cg,
                                                      const float* __restrict__ Wh,
                                                      const unsigned short* __restrict__ vT,
                                                      float* __restrict__ alpha,
                                                      float* __restrict__ C) {
    const int bid = blockIdx.x;
    const int orig = (bid & 7) * 256 + (bid >> 3);
    const int b = orig >> 5;
    const int t0 = (orig & 31) * 8;

    __shared__ __align__(16) short Al[16 * 64];  // [t][r] bf16, swizzled; rows 8..15 = 0
    __shared__ __align__(16) float cvl[49 * 52];
    __shared__ __align__(16) float cgl[8 * 52];
    __shared__ __align__(16) float whl[52];

    const int tid = threadIdx.x;
    for (int i = tid; i < 49 * 49; i += 512) {
        int r = i / 49, k = i - r * 49;
        cvl[r * 52 + k] = cv[(size_t)b * 2401 + i];
    }
    for (int i = tid; i < 8 * 49; i += 512) {
        int t = i / 49, k = i - t * 49;
        cgl[t * 52 + k] = cg[((size_t)b * 256 + t0) * 49 + i];
    }
    Al[512 + tid] = 0;  // rows 8..15 (tid 0..511 covers shorts 512..1023)
    if (tid < 52) whl[tid] = (tid < 49) ? Wh[tid] : 0.f;
    __syncthreads();

    const int wave = tid >> 6;
    const int lane = tid & 63;
    const int quad = lane >> 4, l16 = lane & 15;
    const float4* cvr = (const float4*)(cvl + lane * 52);
    const float4* wh4 = (const float4*)whl;

    // ---- phase 1: z + softmax for row tl = wave; alpha -> global + LDS bf16 ----
    {
        const int tl = wave;
        float z = -INFINITY;
        if (lane < 49) {
            const float4* cgr = (const float4*)(cgl + tl * 52);
            float s = 0.f;
#pragma unroll 4
            for (int kk = 0; kk < 12; ++kk) {
                float4 x = cvr[kk], g = cgr[kk], w = wh4[kk];
                float r0 = __builtin_amdgcn_rcpf(__expf(2.f * (x.x + g.x)) + 1.f);
                float r1 = __builtin_amdgcn_rcpf(__expf(2.f * (x.y + g.y)) + 1.f);
                float r2 = __builtin_amdgcn_rcpf(__expf(2.f * (x.z + g.z)) + 1.f);
                float r3 = __builtin_amdgcn_rcpf(__expf(2.f * (x.w + g.w)) + 1.f);
                s = fmaf(1.f - 2.f * r0, w.x, s);
                s = fmaf(1.f - 2.f * r1, w.y, s);
                s = fmaf(1.f - 2.f * r2, w.z, s);
                s = fmaf(1.f - 2.f * r3, w.w, s);
            }
            {
                float x = cvl[lane * 52 + 48] + cgl[tl * 52 + 48];
                float r0 = __builtin_amdgcn_rcpf(__expf(2.f * x) + 1.f);
                s = fmaf(1.f - 2.f * r0, whl[48], s);
            }
            z = s;
        }
        float m = z;
        for (int off = 32; off; off >>= 1) m = fmaxf(m, __shfl_xor(m, off));
        float p = (lane < 49) ? __expf(z - m) : 0.f;
        float sum = p;
        for (int off = 32; off; off >>= 1) sum += __shfl_xor(sum, off);
        const float val = p * __builtin_amdgcn_rcpf(sum);  // 0 for lane>=49

        const size_t grow = (size_t)b * 256 + t0 + tl;
        if (lane < 49) alpha[grow * 49 + lane] = val;
        const int pos = (((lane >> 3) ^ (tl & 7)) << 3) | (lane & 7);
        Al[tl * 64 + pos] = (short)f2bf_bits(val);
    }
    __syncthreads();  // Al valid; the only phase-2 barrier

    // ---- phase 2: c_t = alpha @ V^T; wave owns h stripe [wave*128, +128) ----
    bf16x8 af[2];
#pragma unroll
    for (int kc = 0; kc < 2; ++kc)
        af[kc] = *(const bf16x8*)(Al + l16 * 64 + (((kc << 2) + quad) ^ (l16 & 7)) * 8);

    const int hb = wave * 128;
    const unsigned short* vb = vT + ((size_t)b * 1024 + hb) * 64;

    floatx4 acc[8] = {};
#pragma unroll
    for (int ns = 0; ns < 8; ++ns) {
        const int row = ns * 16 + l16;  // hb%8==0 -> (hb+row)&7 == row&7
        const unsigned short* vrow = vb + (size_t)row * 64;
        bf16x8 b0 = *(const bf16x8*)(vrow + ((quad ^ (row & 7)) * 8));
        bf16x8 b1 = *(const bf16x8*)(vrow + (((4 + quad) ^ (row & 7)) * 8));
        acc[ns] = __builtin_amdgcn_mfma_f32_16x16x32_bf16(af[0], b0, acc[ns], 0, 0, 0);
        acc[ns] = __builtin_amdgcn_mfma_f32_16x16x32_bf16(af[1], b1, acc[ns], 0, 0, 0);
    }

    if (quad < 2) {  // only t-rows 0..7 are real
#pragma unroll
        for (int ns = 0; ns < 8; ++ns) {
            const int h = hb + ns * 16 + l16;
#pragma unroll
            for (int r = 0; r < 4; ++r) {
                const int t = t0 + quad * 4 + r;
                C[((size_t)b * 256 + t) * 1024 + h] = acc[ns][r];
            }
        }
    }
}

extern "C" void kernel_launch(void* const* d_in, const int* in_sizes, int n_in,
                              void* d_out, int out_size, void* d_ws, size_t ws_size,
                              hipStream_t stream) {
    const float* V   = (const float*)d_in[0];
    const float* h_t = (const float*)d_in[1];
    const float* Wv  = (const float*)d_in[2];
    const float* Wg  = (const float*)d_in[3];
    const float* Wh  = (const float*)d_in[4];

    float* c_t   = (float*)d_out;
    float* alpha = (float*)d_out + 16777216;

    float* cv = (float*)d_ws;                                       // 153664 f
    float* cg = cv + 153664;                                        // 802816 f
    unsigned short* vT = (unsigned short*)((char*)d_ws + 3825920);  // 64*1024*64

    gemm_mfma_tr<<<305 + 512, 256, 0, stream>>>(V, h_t, Wv, Wg, cv, cg, vT);
    zsoftmax_ct<<<2048, 512, 0, stream>>>(cv, cg, Wh, vT, alpha, c_t);
}

// Round 8
// 162.637 us; speedup vs baseline: 1.0695x; 1.0695x over previous
//
#include <hip/hip_runtime.h>
#include <hip/hip_bf16.h>
#include <math.h>
#include <stdint.h>

// Shapes: B=64, T=256, R=49, H=1024
// out = [c_t (B*T*H fp32)] ++ [alpha (B*T*R fp32)]
// ws  = [cv fp32 3136x49][cg fp32 16384x49][vT bf16 64x1024x64 swizzled] (~12.2 MB)
//
// Round 8: revert zsoftmax_ct to the round-5 structure (t-tile 16, grid 1024,
// 2 rows/wave — the 160.2 µs best; round-7's t-tile 8 regressed on per-block
// overheads). ONE change inside phase 1: the 49-deep serial fmaf accumulation
// is split into 4 independent partial sums (s0..s3) to cut the dependent-chain
// depth 4x (latency-bound per round-4/7 counters). GEMM byte-identical round 5.

typedef __attribute__((ext_vector_type(8))) short bf16x8;
typedef __attribute__((ext_vector_type(4))) float floatx4;

static __device__ __forceinline__ bf16x8 pack8(float4 a, float4 b) {
    union { __hip_bfloat162 h[4]; bf16x8 v; } u;
    u.h[0] = __float22bfloat162_rn(make_float2(a.x, a.y));
    u.h[1] = __float22bfloat162_rn(make_float2(a.z, a.w));
    u.h[2] = __float22bfloat162_rn(make_float2(b.x, b.y));
    u.h[3] = __float22bfloat162_rn(make_float2(b.z, b.w));
    return u.v;
}

static __device__ __forceinline__ unsigned short f2bf_bits(float f) {
    union { __hip_bfloat16 h; unsigned short u; } c;
    c.h = __float2bfloat16(f);
    return c.u;
}

// Blocks 0..48: cv = V.Wv^T (M-tile 64); 49..304: cg = h_t.Wg^T (M-tile 64);
// 305..816: transpose V -> vT[b][h][r(pad 64)] bf16, octet-swizzled rows.
// (byte-exact round-5 version)
__global__ __launch_bounds__(256) void gemm_mfma_tr(const float* __restrict__ Av,
                                                    const float* __restrict__ Ag,
                                                    const float* __restrict__ Wv,
                                                    const float* __restrict__ Wg,
                                                    float* __restrict__ Cv,
                                                    float* __restrict__ Cg,
                                                    unsigned short* __restrict__ vT) {
    __shared__ __align__(16) char smem[49 * 132 * 4];  // 25872 B, union
    const int bid = blockIdx.x;
    const int tid = threadIdx.x;

    if (bid >= 305) {
        // ---- V transpose: one (b, 128-h slice) per block ----
        float* Ts = (float*)smem;  // [49][132]
        const int tb = bid - 305;
        const int b = tb >> 3;
        const int h0 = (tb & 7) * 128;
        for (int i = tid; i < 49 * 32; i += 256) {
            const int r = i >> 5, hq = i & 31;
            *(float4*)(Ts + r * 132 + hq * 4) =
                *(const float4*)(Av + ((size_t)b * 49 + r) * 1024 + h0 + hq * 4);
        }
        __syncthreads();
        const int h = tid & 127;
        const int half = tid >> 7;  // 0: r 0..31 (octets 0..3), 1: r 32..63 (4..7)
        float f[32];
#pragma unroll
        for (int j = 0; j < 32; ++j) {
            const int r = half * 32 + j;
            f[j] = (r < 49) ? Ts[r * 132 + h] : 0.f;
        }
        const size_t rowbase = ((size_t)b * 1024 + h0 + h) * 64;
#pragma unroll
        for (int o2 = 0; o2 < 4; ++o2) {
            const int o = half * 4 + o2;
            bf16x8 v = pack8(make_float4(f[o2*8+0], f[o2*8+1], f[o2*8+2], f[o2*8+3]),
                             make_float4(f[o2*8+4], f[o2*8+5], f[o2*8+6], f[o2*8+7]));
            *(bf16x8*)(vT + rowbase + (size_t)((o ^ (h & 7)) * 8)) = v;
        }
        return;
    }

    // ---- GEMM C[m][n] = sum_k A[m][k]*W[n][k], M-tile 64, K=1024, N=49->64 ----
    short* As = (short*)smem;           // [64][64] bf16, octet-swizzled
    short* Ws = (short*)(smem + 8192);  // [64][64]
    const float* A; const float* W; float* C; int m0;
    if (bid < 49) { A = Av; W = Wv; C = Cv; m0 = bid * 64; }
    else          { A = Ag; W = Wg; C = Cg; m0 = (bid - 49) * 64; }

    const int wave = tid >> 6, lane = tid & 63;
    const int quad = lane >> 4, l16 = lane & 15;

    floatx4 acc[4] = {};  // wave owns m [wave*16,+16) x n [0,64)

    // A staging: round-2 pattern, applied to rows arow and arow+32.
    const int arow = tid >> 3, ag = tid & 7;
    const float* aptr = A + (size_t)(m0 + arow) * 1024 + ag * 8;
    const float* bptr = aptr + 32 * 1024;  // row arow+32, same octet
    // W staging: byte-identical round-2 code.
    const int wrow = tid >> 2, wq = tid & 3;
    const bool wvalid = wrow < 49;
    const float* wptr = W + (size_t)wrow * 1024 + wq * 16;

    float4 a0 = *(const float4*)(aptr);
    float4 a1 = *(const float4*)(aptr + 4);
    float4 b0 = *(const float4*)(bptr);
    float4 b1 = *(const float4*)(bptr + 4);
    float4 w0 = make_float4(0.f,0.f,0.f,0.f), w1 = w0, w2 = w0, w3 = w0;
    if (wvalid) {
        w0 = *(const float4*)(wptr);
        w1 = *(const float4*)(wptr + 4);
        w2 = *(const float4*)(wptr + 8);
        w3 = *(const float4*)(wptr + 12);
    }

    for (int kc = 0; kc < 1024; kc += 64) {
        __syncthreads();
        *(bf16x8*)(As + arow * 64 + (ag ^ (arow & 7)) * 8)        = pack8(a0, a1);
        *(bf16x8*)(As + (arow + 32) * 64 + (ag ^ (arow & 7)) * 8) = pack8(b0, b1);
        *(bf16x8*)(Ws + wrow * 64 + ((wq * 2) ^ (wrow & 7)) * 8)     = pack8(w0, w1);
        *(bf16x8*)(Ws + wrow * 64 + ((wq * 2 + 1) ^ (wrow & 7)) * 8) = pack8(w2, w3);
        __syncthreads();
        if (kc < 960) {  // prefetch next tile; latency hides under MFMA below
            a0 = *(const float4*)(aptr + kc + 64);
            a1 = *(const float4*)(aptr + kc + 68);
            b0 = *(const float4*)(bptr + kc + 64);
            b1 = *(const float4*)(bptr + kc + 68);
            if (wvalid) {
                w0 = *(const float4*)(wptr + kc + 64);
                w1 = *(const float4*)(wptr + kc + 68);
                w2 = *(const float4*)(wptr + kc + 72);
                w3 = *(const float4*)(wptr + kc + 76);
            }
        }
#pragma unroll
        for (int s = 0; s < 2; ++s) {
            const int am = wave * 16 + l16;
            bf16x8 af = *(const bf16x8*)(As + am * 64 + (((s << 2) + quad) ^ (am & 7)) * 8);
#pragma unroll
            for (int nt = 0; nt < 4; ++nt) {
                const int wn = nt * 16 + l16;
                bf16x8 bf = *(const bf16x8*)(Ws + wn * 64 + (((s << 2) + quad) ^ (wn & 7)) * 8);
                acc[nt] = __builtin_amdgcn_mfma_f32_16x16x32_bf16(af, bf, acc[nt], 0, 0, 0);
            }
        }
    }

#pragma unroll
    for (int nt = 0; nt < 4; ++nt) {
        const int n = nt * 16 + l16;
        if (n < 49) {
#pragma unroll
            for (int r = 0; r < 4; ++r) {
                const int m = m0 + wave * 16 + quad * 4 + r;
                C[(size_t)m * 49 + n] = acc[nt][r];
            }
        }
    }
}

// Fused: z[b,t,r] = sum_k tanh(cv[b,r,k]+cg[b,t,k])*Wh[k]; alpha=softmax_r(z);
// c_t[b,t,h] = sum_r alpha*V via bf16 MFMA with B-fragments read straight
// from global vT (L2-resident). Block = (b, 16-row t-tile), 512 threads/8 waves,
// grid 64*16=1024. XCD-chunked bid swizzle. Round-5 structure; phase-1 sum
// split into 4 independent partial accumulators (chain depth 49 -> ~13).
__global__ __launch_bounds__(512, 8) void zsoftmax_ct(const float* __restrict__ cv,
                                                      const float* __restrict__ cg,
                                                      const float* __restrict__ Wh,
                                                      const unsigned short* __restrict__ vT,
                                                      float* __restrict__ alpha,
                                                      float* __restrict__ C) {
    const int bid = blockIdx.x;
    const int orig = (bid & 7) * 128 + (bid >> 3);
    const int b = orig >> 4;
    const int t0 = (orig & 15) * 16;

    __shared__ __align__(16) short Al[16 * 64];  // [t][r] bf16, swizzled
    __shared__ __align__(16) float cvl[49 * 52];
    __shared__ __align__(16) float cgl[16 * 52];
    __shared__ __align__(16) float whl[52];

    const int tid = threadIdx.x;
    for (int i = tid; i < 49 * 49; i += 512) {
        int r = i / 49, k = i - r * 49;
        cvl[r * 52 + k] = cv[(size_t)b * 2401 + i];
    }
    for (int i = tid; i < 16 * 49; i += 512) {
        int t = i / 49, k = i - t * 49;
        cgl[t * 52 + k] = cg[((size_t)b * 256 + t0) * 49 + i];
    }
    if (tid < 52) whl[tid] = (tid < 49) ? Wh[tid] : 0.f;
    __syncthreads();

    const int wave = tid >> 6;
    const int lane = tid & 63;
    const int quad = lane >> 4, l16 = lane & 15;
    const float4* cvr = (const float4*)(cvl + lane * 52);
    const float4* wh4 = (const float4*)whl;

    // ---- phase 1: z + softmax; alpha -> global fp32 + LDS bf16 (swizzled) ----
#pragma unroll
    for (int i = 0; i < 2; ++i) {
        const int tl = wave * 2 + i;
        float z = -INFINITY;
        if (lane < 49) {
            const float4* cgr = (const float4*)(cgl + tl * 52);
            float s0 = 0.f, s1 = 0.f, s2 = 0.f, s3 = 0.f;
#pragma unroll 4
            for (int kk = 0; kk < 12; ++kk) {
                float4 x = cvr[kk], g = cgr[kk], w = wh4[kk];
                float r0 = __builtin_amdgcn_rcpf(__expf(2.f * (x.x + g.x)) + 1.f);
                float r1 = __builtin_amdgcn_rcpf(__expf(2.f * (x.y + g.y)) + 1.f);
                float r2 = __builtin_amdgcn_rcpf(__expf(2.f * (x.z + g.z)) + 1.f);
                float r3 = __builtin_amdgcn_rcpf(__expf(2.f * (x.w + g.w)) + 1.f);
                s0 = fmaf(1.f - 2.f * r0, w.x, s0);
                s1 = fmaf(1.f - 2.f * r1, w.y, s1);
                s2 = fmaf(1.f - 2.f * r2, w.z, s2);
                s3 = fmaf(1.f - 2.f * r3, w.w, s3);
            }
            {
                float x = cvl[lane * 52 + 48] + cgl[tl * 52 + 48];
                float r0 = __builtin_amdgcn_rcpf(__expf(2.f * x) + 1.f);
                s0 = fmaf(1.f - 2.f * r0, whl[48], s0);
            }
            z = (s0 + s1) + (s2 + s3);
        }
        float m = z;
        for (int off = 32; off; off >>= 1) m = fmaxf(m, __shfl_xor(m, off));
        float p = (lane < 49) ? __expf(z - m) : 0.f;
        float sum = p;
        for (int off = 32; off; off >>= 1) sum += __shfl_xor(sum, off);
        const float val = p * __builtin_amdgcn_rcpf(sum);  // 0 for lane>=49

        const size_t grow = (size_t)b * 256 + t0 + tl;
        if (lane < 49) alpha[grow * 49 + lane] = val;
        const int pos = (((lane >> 3) ^ (tl & 7)) << 3) | (lane & 7);
        Al[tl * 64 + pos] = (short)f2bf_bits(val);
    }
    __syncthreads();  // Al valid; the only phase-2 barrier

    // ---- phase 2: c_t = alpha @ V^T; wave owns h stripe [wave*128, +128) ----
    bf16x8 af[2];
#pragma unroll
    for (int kc = 0; kc < 2; ++kc)
        af[kc] = *(const bf16x8*)(Al + l16 * 64 + (((kc << 2) + quad) ^ (l16 & 7)) * 8);

    const int hb = wave * 128;
    const unsigned short* vb = vT + ((size_t)b * 1024 + hb) * 64;

    floatx4 acc[8] = {};
#pragma unroll
    for (int ns = 0; ns < 8; ++ns) {
        const int row = ns * 16 + l16;  // hb%8==0 -> (hb+row)&7 == row&7
        const unsigned short* vrow = vb + (size_t)row * 64;
        bf16x8 b0 = *(const bf16x8*)(vrow + ((quad ^ (row & 7)) * 8));
        bf16x8 b1 = *(const bf16x8*)(vrow + (((4 + quad) ^ (row & 7)) * 8));
        acc[ns] = __builtin_amdgcn_mfma_f32_16x16x32_bf16(af[0], b0, acc[ns], 0, 0, 0);
        acc[ns] = __builtin_amdgcn_mfma_f32_16x16x32_bf16(af[1], b1, acc[ns], 0, 0, 0);
    }

#pragma unroll
    for (int ns = 0; ns < 8; ++ns) {
        const int h = hb + ns * 16 + l16;
#pragma unroll
        for (int r = 0; r < 4; ++r) {
            const int t = t0 + quad * 4 + r;
            C[((size_t)b * 256 + t) * 1024 + h] = acc[ns][r];
        }
    }
}

extern "C" void kernel_launch(void* const* d_in, const int* in_sizes, int n_in,
                              void* d_out, int out_size, void* d_ws, size_t ws_size,
                              hipStream_t stream) {
    const float* V   = (const float*)d_in[0];
    const float* h_t = (const float*)d_in[1];
    const float* Wv  = (const float*)d_in[2];
    const float* Wg  = (const float*)d_in[3];
    const float* Wh  = (const float*)d_in[4];

    float* c_t   = (float*)d_out;
    float* alpha = (float*)d_out + 16777216;

    float* cv = (float*)d_ws;                                       // 153664 f
    float* cg = cv + 153664;                                        // 802816 f
    unsigned short* vT = (unsigned short*)((char*)d_ws + 3825920);  // 64*1024*64

    gemm_mfma_tr<<<305 + 512, 256, 0, stream>>>(V, h_t, Wv, Wg, cv, cg, vT);
    zsoftmax_ct<<<1024, 512, 0, stream>>>(cv, cg, Wh, vT, alpha, c_t);
}

// Round 9
// 157.751 us; speedup vs baseline: 1.1026x; 1.0310x over previous
//
#include <hip/hip_runtime.h>
#include <hip/hip_bf16.h>
#include <math.h>
#include <stdint.h>

// Shapes: B=64, T=256, R=49, H=1024
// out = [c_t (B*T*H fp32)] ++ [alpha (B*T*R fp32)]
// ws  = [cv0|cv1 fp32 3136x49 each][cg0|cg1 fp32 16384x49 each]
//       [vT bf16 64x1024x64 swizzled]  (~16 MB)
//
// Round 9: GEMM K-split 2. 305 long GEMM blocks on 256 CUs left ~49 CUs
// running 2 blocks (2x tail). Now 610 half-K blocks (~2.4/CU) write partial
// cv/cg buffers; zsm staging sums the pair. Inner GEMM body byte-equivalent
// to verified round-5 M64 (column window + trip count only). zsm phase 1
// reverted to r5-exact single accumulator.

typedef __attribute__((ext_vector_type(8))) short bf16x8;
typedef __attribute__((ext_vector_type(4))) float floatx4;

static __device__ __forceinline__ bf16x8 pack8(float4 a, float4 b) {
    union { __hip_bfloat162 h[4]; bf16x8 v; } u;
    u.h[0] = __float22bfloat162_rn(make_float2(a.x, a.y));
    u.h[1] = __float22bfloat162_rn(make_float2(a.z, a.w));
    u.h[2] = __float22bfloat162_rn(make_float2(b.x, b.y));
    u.h[3] = __float22bfloat162_rn(make_float2(b.z, b.w));
    return u.v;
}

static __device__ __forceinline__ unsigned short f2bf_bits(float f) {
    union { __hip_bfloat16 h; unsigned short u; } c;
    c.h = __float2bfloat16(f);
    return c.u;
}

// Blocks 0..609: GEMM, ks = bid&1 (K half), g = bid>>1:
//   g 0..48  -> cv partial (M-tile 64), g 49..304 -> cg partial (M-tile 64).
// Blocks 610..1121: transpose V -> vT[b][h][r(pad 64)] bf16, octet-swizzled.
__global__ __launch_bounds__(256) void gemm_mfma_tr(const float* __restrict__ Av,
                                                    const float* __restrict__ Ag,
                                                    const float* __restrict__ Wv,
                                                    const float* __restrict__ Wg,
                                                    float* __restrict__ Cv0,
                                                    float* __restrict__ Cv1,
                                                    float* __restrict__ Cg0,
                                                    float* __restrict__ Cg1,
                                                    unsigned short* __restrict__ vT) {
    __shared__ __align__(16) char smem[49 * 132 * 4];  // 25872 B, union
    const int bid = blockIdx.x;
    const int tid = threadIdx.x;

    if (bid >= 610) {
        // ---- V transpose: one (b, 128-h slice) per block (verified body) ----
        float* Ts = (float*)smem;  // [49][132]
        const int tb = bid - 610;
        const int b = tb >> 3;
        const int h0 = (tb & 7) * 128;
        for (int i = tid; i < 49 * 32; i += 256) {
            const int r = i >> 5, hq = i & 31;
            *(float4*)(Ts + r * 132 + hq * 4) =
                *(const float4*)(Av + ((size_t)b * 49 + r) * 1024 + h0 + hq * 4);
        }
        __syncthreads();
        const int h = tid & 127;
        const int half = tid >> 7;  // 0: r 0..31 (octets 0..3), 1: r 32..63 (4..7)
        float f[32];
#pragma unroll
        for (int j = 0; j < 32; ++j) {
            const int r = half * 32 + j;
            f[j] = (r < 49) ? Ts[r * 132 + h] : 0.f;
        }
        const size_t rowbase = ((size_t)b * 1024 + h0 + h) * 64;
#pragma unroll
        for (int o2 = 0; o2 < 4; ++o2) {
            const int o = half * 4 + o2;
            bf16x8 v = pack8(make_float4(f[o2*8+0], f[o2*8+1], f[o2*8+2], f[o2*8+3]),
                             make_float4(f[o2*8+4], f[o2*8+5], f[o2*8+6], f[o2*8+7]));
            *(bf16x8*)(vT + rowbase + (size_t)((o ^ (h & 7)) * 8)) = v;
        }
        return;
    }

    // ---- GEMM partial: C[m][n] = sum_{k in half ks} A[m][k]*W[n][k] ----
    short* As = (short*)smem;           // [64][64] bf16, octet-swizzled
    short* Ws = (short*)(smem + 8192);  // [64][64]
    const int ks = bid & 1;             // K half: cols [ks*512, ks*512+512)
    const int g = bid >> 1;
    const float* A; const float* W; float* C; int m0;
    if (g < 49) { A = Av; W = Wv; C = ks ? Cv1 : Cv0; m0 = g * 64; }
    else        { A = Ag; W = Wg; C = ks ? Cg1 : Cg0; m0 = (g - 49) * 64; }

    const int wave = tid >> 6, lane = tid & 63;
    const int quad = lane >> 4, l16 = lane & 15;

    floatx4 acc[4] = {};  // wave owns m [wave*16,+16) x n [0,64)

    // A staging: verified round-2 pattern, rows arow and arow+32, K window ks*512.
    const int arow = tid >> 3, ag = tid & 7;
    const float* aptr = A + (size_t)(m0 + arow) * 1024 + ks * 512 + ag * 8;
    const float* bptr = aptr + 32 * 1024;  // row arow+32, same octet
    // W staging: verified round-2 code, K window ks*512.
    const int wrow = tid >> 2, wq = tid & 3;
    const bool wvalid = wrow < 49;
    const float* wptr = W + (size_t)wrow * 1024 + ks * 512 + wq * 16;

    float4 a0 = *(const float4*)(aptr);
    float4 a1 = *(const float4*)(aptr + 4);
    float4 b0 = *(const float4*)(bptr);
    float4 b1 = *(const float4*)(bptr + 4);
    float4 w0 = make_float4(0.f,0.f,0.f,0.f), w1 = w0, w2 = w0, w3 = w0;
    if (wvalid) {
        w0 = *(const float4*)(wptr);
        w1 = *(const float4*)(wptr + 4);
        w2 = *(const float4*)(wptr + 8);
        w3 = *(const float4*)(wptr + 12);
    }

    for (int kc = 0; kc < 512; kc += 64) {
        __syncthreads();
        *(bf16x8*)(As + arow * 64 + (ag ^ (arow & 7)) * 8)        = pack8(a0, a1);
        *(bf16x8*)(As + (arow + 32) * 64 + (ag ^ (arow & 7)) * 8) = pack8(b0, b1);
        *(bf16x8*)(Ws + wrow * 64 + ((wq * 2) ^ (wrow & 7)) * 8)     = pack8(w0, w1);
        *(bf16x8*)(Ws + wrow * 64 + ((wq * 2 + 1) ^ (wrow & 7)) * 8) = pack8(w2, w3);
        __syncthreads();
        if (kc < 448) {  // prefetch next tile; stays within the 512-col window
            a0 = *(const float4*)(aptr + kc + 64);
            a1 = *(const float4*)(aptr + kc + 68);
            b0 = *(const float4*)(bptr + kc + 64);
            b1 = *(const float4*)(bptr + kc + 68);
            if (wvalid) {
                w0 = *(const float4*)(wptr + kc + 64);
                w1 = *(const float4*)(wptr + kc + 68);
                w2 = *(const float4*)(wptr + kc + 72);
                w3 = *(const float4*)(wptr + kc + 76);
            }
        }
#pragma unroll
        for (int s = 0; s < 2; ++s) {
            const int am = wave * 16 + l16;
            bf16x8 af = *(const bf16x8*)(As + am * 64 + (((s << 2) + quad) ^ (am & 7)) * 8);
#pragma unroll
            for (int nt = 0; nt < 4; ++nt) {
                const int wn = nt * 16 + l16;
                bf16x8 bf = *(const bf16x8*)(Ws + wn * 64 + (((s << 2) + quad) ^ (wn & 7)) * 8);
                acc[nt] = __builtin_amdgcn_mfma_f32_16x16x32_bf16(af, bf, acc[nt], 0, 0, 0);
            }
        }
    }

#pragma unroll
    for (int nt = 0; nt < 4; ++nt) {
        const int n = nt * 16 + l16;
        if (n < 49) {
#pragma unroll
            for (int r = 0; r < 4; ++r) {
                const int m = m0 + wave * 16 + quad * 4 + r;
                C[(size_t)m * 49 + n] = acc[nt][r];
            }
        }
    }
}

// Fused: z[b,t,r] = sum_k tanh(cv[b,r,k]+cg[b,t,k])*Wh[k]; alpha=softmax_r(z);
// c_t[b,t,h] = sum_r alpha*V via bf16 MFMA with B-fragments read straight
// from global vT (L2-resident). Block = (b, 16-row t-tile), 512 threads/8 waves,
// grid 64*16=1024. XCD-chunked bid swizzle. Round-5-exact body except the
// staging loops sum the two K-split partial buffers.
__global__ __launch_bounds__(512, 8) void zsoftmax_ct(const float* __restrict__ cv0,
                                                      const float* __restrict__ cv1,
                                                      const float* __restrict__ cg0,
                                                      const float* __restrict__ cg1,
                                                      const float* __restrict__ Wh,
                                                      const unsigned short* __restrict__ vT,
                                                      float* __restrict__ alpha,
                                                      float* __restrict__ C) {
    const int bid = blockIdx.x;
    const int orig = (bid & 7) * 128 + (bid >> 3);
    const int b = orig >> 4;
    const int t0 = (orig & 15) * 16;

    __shared__ __align__(16) short Al[16 * 64];  // [t][r] bf16, swizzled
    __shared__ __align__(16) float cvl[49 * 52];
    __shared__ __align__(16) float cgl[16 * 52];
    __shared__ __align__(16) float whl[52];

    const int tid = threadIdx.x;
    for (int i = tid; i < 49 * 49; i += 512) {
        int r = i / 49, k = i - r * 49;
        cvl[r * 52 + k] = cv0[(size_t)b * 2401 + i] + cv1[(size_t)b * 2401 + i];
    }
    for (int i = tid; i < 16 * 49; i += 512) {
        int t = i / 49, k = i - t * 49;
        const size_t idx = ((size_t)b * 256 + t0) * 49 + i;
        cgl[t * 52 + k] = cg0[idx] + cg1[idx];
    }
    if (tid < 52) whl[tid] = (tid < 49) ? Wh[tid] : 0.f;
    __syncthreads();

    const int wave = tid >> 6;
    const int lane = tid & 63;
    const int quad = lane >> 4, l16 = lane & 15;
    const float4* cvr = (const float4*)(cvl + lane * 52);
    const float4* wh4 = (const float4*)whl;

    // ---- phase 1: z + softmax; alpha -> global fp32 + LDS bf16 (swizzled) ----
#pragma unroll
    for (int i = 0; i < 2; ++i) {
        const int tl = wave * 2 + i;
        float z = -INFINITY;
        if (lane < 49) {
            const float4* cgr = (const float4*)(cgl + tl * 52);
            float s = 0.f;
#pragma unroll 4
            for (int kk = 0; kk < 12; ++kk) {
                float4 x = cvr[kk], g = cgr[kk], w = wh4[kk];
                float r0 = __builtin_amdgcn_rcpf(__expf(2.f * (x.x + g.x)) + 1.f);
                float r1 = __builtin_amdgcn_rcpf(__expf(2.f * (x.y + g.y)) + 1.f);
                float r2 = __builtin_amdgcn_rcpf(__expf(2.f * (x.z + g.z)) + 1.f);
                float r3 = __builtin_amdgcn_rcpf(__expf(2.f * (x.w + g.w)) + 1.f);
                s = fmaf(1.f - 2.f * r0, w.x, s);
                s = fmaf(1.f - 2.f * r1, w.y, s);
                s = fmaf(1.f - 2.f * r2, w.z, s);
                s = fmaf(1.f - 2.f * r3, w.w, s);
            }
            {
                float x = cvl[lane * 52 + 48] + cgl[tl * 52 + 48];
                float r0 = __builtin_amdgcn_rcpf(__expf(2.f * x) + 1.f);
                s = fmaf(1.f - 2.f * r0, whl[48], s);
            }
            z = s;
        }
        float m = z;
        for (int off = 32; off; off >>= 1) m = fmaxf(m, __shfl_xor(m, off));
        float p = (lane < 49) ? __expf(z - m) : 0.f;
        float sum = p;
        for (int off = 32; off; off >>= 1) sum += __shfl_xor(sum, off);
        const float val = p * __builtin_amdgcn_rcpf(sum);  // 0 for lane>=49

        const size_t grow = (size_t)b * 256 + t0 + tl;
        if (lane < 49) alpha[grow * 49 + lane] = val;
        const int pos = (((lane >> 3) ^ (tl & 7)) << 3) | (lane & 7);
        Al[tl * 64 + pos] = (short)f2bf_bits(val);
    }
    __syncthreads();  // Al valid; the only phase-2 barrier

    // ---- phase 2: c_t = alpha @ V^T; wave owns h stripe [wave*128, +128) ----
    bf16x8 af[2];
#pragma unroll
    for (int kc = 0; kc < 2; ++kc)
        af[kc] = *(const bf16x8*)(Al + l16 * 64 + (((kc << 2) + quad) ^ (l16 & 7)) * 8);

    const int hb = wave * 128;
    const unsigned short* vb = vT + ((size_t)b * 1024 + hb) * 64;

    floatx4 acc[8] = {};
#pragma unroll
    for (int ns = 0; ns < 8; ++ns) {
        const int row = ns * 16 + l16;  // hb%8==0 -> (hb+row)&7 == row&7
        const unsigned short* vrow = vb + (size_t)row * 64;
        bf16x8 b0 = *(const bf16x8*)(vrow + ((quad ^ (row & 7)) * 8));
        bf16x8 b1 = *(const bf16x8*)(vrow + (((4 + quad) ^ (row & 7)) * 8));
        acc[ns] = __builtin_amdgcn_mfma_f32_16x16x32_bf16(af[0], b0, acc[ns], 0, 0, 0);
        acc[ns] = __builtin_amdgcn_mfma_f32_16x16x32_bf16(af[1], b1, acc[ns], 0, 0, 0);
    }

#pragma unroll
    for (int ns = 0; ns < 8; ++ns) {
        const int h = hb + ns * 16 + l16;
#pragma unroll
        for (int r = 0; r < 4; ++r) {
            const int t = t0 + quad * 4 + r;
            C[((size_t)b * 256 + t) * 1024 + h] = acc[ns][r];
        }
    }
}

extern "C" void kernel_launch(void* const* d_in, const int* in_sizes, int n_in,
                              void* d_out, int out_size, void* d_ws, size_t ws_size,
                              hipStream_t stream) {
    const float* V   = (const float*)d_in[0];
    const float* h_t = (const float*)d_in[1];
    const float* Wv  = (const float*)d_in[2];
    const float* Wg  = (const float*)d_in[3];
    const float* Wh  = (const float*)d_in[4];

    float* c_t   = (float*)d_out;
    float* alpha = (float*)d_out + 16777216;

    float* cv0 = (float*)d_ws;                                      // 153664 f
    float* cv1 = cv0 + 153664;                                      // 153664 f
    float* cg0 = cv1 + 153664;                                      // 802816 f
    float* cg1 = cg0 + 802816;                                      // 802816 f
    unsigned short* vT = (unsigned short*)((char*)d_ws + 7651840);  // 64*1024*64

    gemm_mfma_tr<<<610 + 512, 256, 0, stream>>>(V, h_t, Wv, Wg, cv0, cv1, cg0, cg1, vT);
    zsoftmax_ct<<<1024, 512, 0, stream>>>(cv0, cv1, cg0, cg1, Wh, vT, alpha, c_t);
}